// Round 11
// baseline (49.793 us; speedup 1.0000x reference)
//
#include <hip/hip_runtime.h>
#include <math.h>

typedef _Float16 half8 __attribute__((ext_vector_type(8)));
typedef float f32x4 __attribute__((ext_vector_type(4)));

#define RLT (1.0f/0.07f)

// out layout (flat fp32):
//   A      [256,196]  @ 0
//   logits [256,258]  @ 50176
//   Pos    [256,196]  @ 116224
//   Neg    [256,196]  @ 166400
//   A0_ref [256,256]  @ 216576

__device__ __forceinline__ void gll16(const void* g, void* l) {
    __builtin_amdgcn_global_load_lds(
        (const __attribute__((address_space(1))) void*)g,
        (__attribute__((address_space(3))) void*)l, 16, 0, 0);
}

// aud_pk layout: [c>>3][m][c&7] fp16 — 64 groups x 256 m x 8 halves (16B per (cg,m))
__global__ __launch_bounds__(256) void prep_aud_pk(const float* __restrict__ aud,
                                                   _Float16* __restrict__ aud_pk) {
    int m = blockIdx.x, t = threadIdx.x;
    float a0 = aud[m * 512 + t];
    float a1 = aud[m * 512 + 256 + t];
    float s = a0 * a0 + a1 * a1;
    #pragma unroll
    for (int off = 32; off; off >>= 1) s += __shfl_down(s, off, 64);
    __shared__ float wsum[4];
    __shared__ float rns;
    if ((t & 63) == 0) wsum[t >> 6] = s;
    __syncthreads();
    if (t == 0) rns = 1.0f / fmaxf(sqrtf(wsum[0] + wsum[1] + wsum[2] + wsum[3]), 1e-12f);
    __syncthreads();
    float rn = rns;
    int c0 = t, c1 = t + 256;
    aud_pk[(c0 >> 3) * 2048 + m * 8 + (c0 & 7)] = (_Float16)(a0 * rn);
    aud_pk[(c1 >> 3) * 2048 + m * 8 + (c1 & 7)] = (_Float16)(a1 * rn);
}

// ONE block per n (256 blocks, 512 thr, 1 block/CU, 256-VGPR budget).
// Full 196-row x 256-m tile; acc[7][4] (112 AGPR). Single barrier domain:
// B: global_load_lds dbuf; A: 16 dwords/thread 2-slot reg prefetch -> cvt -> ds_write.
// Counted-vmcnt barrier: vmcnt(16) drains only the 2 B gll16s; the 16 A(t+2)
// loads stay in flight across the barrier -> HBM stream never stalls.
__global__ __launch_bounds__(512, 2) void av_one(const float* __restrict__ img,
                                                 const _Float16* __restrict__ aud_pk,
                                                 float* __restrict__ out) {
    const int n = blockIdx.x;
    const int tid = threadIdx.x;
    const int w = tid >> 6, l = tid & 63;
    const int q = w & 3;        // m-quarter: cols 64q..64q+63
    const int hh = w >> 2;      // hw half: 0 -> rows 0..111 (7 tiles), 1 -> 112..207 (6 tiles)
    const int HT = hh ? 6 : 7;
    const int kk = l >> 4, lm = l & 15;

    __shared__ _Float16 __align__(16) Abuf[2][4][208][8];  // [buf][kg][row][j] 26.6 KB
    __shared__ _Float16 __align__(16) Bbuf[2][4][256][8];  // [buf][kg][m][j]   32.8 KB
    __shared__ float nrm_parts[2][196];
    __shared__ float rnorm_s[208];
    __shared__ float red_max[2][256], red_sw[2][256], red_swa[2][256];
    __shared__ float diag_parts[2][4][4];

    // zero the pad rows (196..207) of both A buffers once (never overwritten)
    if (tid < 96) {
        int b = tid / 48, rem = tid % 48, kg = rem / 12, row = 196 + rem % 12;
        *(float4*)&Abuf[b][kg][row][0] = make_float4(0.f, 0.f, 0.f, 0.f);
    }

    const float* imgn = img + (size_t)n * (512 * 196);
    const bool act = tid < 392;            // A staging: fixed hw row, 16 consecutive c
    const int p   = act ? tid / 196 : 0;   // c half within the 32-c step
    const int hwl = act ? tid % 196 : 0;   // row (dummies clamp to row 0)
    float nrm = 0.f;
    float av0[16], av1[16];

    // ---- B stage via global_load_lds: all 512 threads, 2 chunks each (tid, tid+512)
    #define STAGE_B(t, buf)                                                         \
        do {                                                                        \
            const _Float16* g0 = aud_pk + (((size_t)(t) * 1024 + tid) << 3);        \
            _Float16* l0 = &Bbuf[buf][0][0][0] + ((w * 64) << 3);                   \
            gll16(g0, l0);                                                          \
            gll16(g0 + 4096, l0 + 4096);                                            \
        } while (0)

    // ---- A loads: ALL threads issue 16 dwords (uniform per-wave vmcnt);
    //      dummies read row 0 (broadcast); keep-alive asm prevents DCE (rule #17)
    #define LOAD_A_TO(dst, t)                                                       \
        do {                                                                        \
            const float* src = imgn + ((size_t)(32 * (t) + p * 16)) * 196 + hwl;    \
            _Pragma("unroll")                                                       \
            for (int i = 0; i < 16; i++) dst[i] = src[i * 196];                     \
            asm volatile("" :: "v"(dst[0]), "v"(dst[1]), "v"(dst[2]), "v"(dst[3]),  \
                               "v"(dst[4]), "v"(dst[5]), "v"(dst[6]), "v"(dst[7])); \
            asm volatile("" :: "v"(dst[8]), "v"(dst[9]), "v"(dst[10]), "v"(dst[11]),\
                               "v"(dst[12]), "v"(dst[13]), "v"(dst[14]), "v"(dst[15])); \
        } while (0)

    #define STAGE_A_FROM(srcv, buf)                                                 \
        do {                                                                        \
            if (act) {                                                              \
                half8 h0, h1;                                                       \
                _Pragma("unroll")                                                   \
                for (int i = 0; i < 8; i++) {                                       \
                    h0[i] = (_Float16)srcv[i];                                      \
                    h1[i] = (_Float16)srcv[8 + i];                                  \
                    nrm += srcv[i] * srcv[i] + srcv[8 + i] * srcv[8 + i];           \
                }                                                                   \
                *(half8*)&Abuf[buf][2 * p][hwl][0]     = h0;                        \
                *(half8*)&Abuf[buf][2 * p + 1][hwl][0] = h1;                        \
            }                                                                       \
        } while (0)

    // ---- prologue: stage step 0 (B gll16 + A cvt), prefetch A(1)->av1
    STAGE_B(0, 0);
    asm volatile("" ::: "memory");
    LOAD_A_TO(av0, 0);
    asm volatile("" ::: "memory");
    STAGE_A_FROM(av0, 0);    // implicit vmcnt wait drains A(0) AND older B gll16s
    LOAD_A_TO(av1, 1);
    asm volatile("s_waitcnt lgkmcnt(0)" ::: "memory");
    __builtin_amdgcn_s_barrier();
    __builtin_amdgcn_sched_barrier(0);

    f32x4 acc[7][4];
    #pragma unroll
    for (int ht = 0; ht < 7; ht++)
        #pragma unroll
        for (int mt = 0; mt < 4; mt++)
            acc[ht][mt] = (f32x4){0.f, 0.f, 0.f, 0.f};

    // per-lane LDS fragment offsets (in halves)
    const int aoff = kk * 1664 + (hh * 112 + lm) * 8;  // + ht*128
    const int boff = kk * 2048 + (q * 64 + lm) * 8;    // + mt*128

    // step t (reads buf cur=t&1):
    //   [B gll16(t+1)->nb] [A loads(t+2)->loadSlot] [ds_read frags + MFMA]
    //   [cvt+ds_write A(t+1) from stageSlot] [lgkm0; vmcnt(16); s_barrier]
    #define STEP(t, cur, loadSlot, stageSlot)                                       \
        do {                                                                        \
            const int nb_ = (cur) ^ 1;                                              \
            if ((t) <= 14) STAGE_B((t) + 1, nb_);                                   \
            asm volatile("" ::: "memory");                                          \
            if ((t) <= 13) LOAD_A_TO(loadSlot, (t) + 2);                            \
            asm volatile("" ::: "memory");                                          \
            {                                                                       \
                const _Float16* Ab = &Abuf[cur][0][0][0];                           \
                const _Float16* Bb = &Bbuf[cur][0][0][0];                           \
                half8 afrag[7];                                                     \
                _Pragma("unroll")                                                   \
                for (int ht = 0; ht < 7; ht++)                                      \
                    if (ht < HT) afrag[ht] = *(const half8*)(Ab + aoff + ht * 128); \
                __builtin_amdgcn_s_setprio(1);                                      \
                _Pragma("unroll")                                                   \
                for (int mt = 0; mt < 4; mt++) {                                    \
                    half8 bfrag = *(const half8*)(Bb + boff + mt * 128);            \
                    _Pragma("unroll")                                               \
                    for (int ht = 0; ht < 7; ht++)                                  \
                        if (ht < HT)                                                \
                            acc[ht][mt] = __builtin_amdgcn_mfma_f32_16x16x32_f16(   \
                                afrag[ht], bfrag, acc[ht][mt], 0, 0, 0);            \
                }                                                                   \
                __builtin_amdgcn_s_setprio(0);                                      \
            }                                                                       \
            __builtin_amdgcn_sched_barrier(0);                                      \
            if ((t) <= 14) STAGE_A_FROM(stageSlot, nb_);                            \
            if ((t) < 15) {                                                         \
                asm volatile("s_waitcnt lgkmcnt(0)" ::: "memory");                  \
                if ((t) <= 13) asm volatile("s_waitcnt vmcnt(16)" ::: "memory");    \
                else           asm volatile("s_waitcnt vmcnt(0)" ::: "memory");     \
                __builtin_amdgcn_s_barrier();                                       \
                __builtin_amdgcn_sched_barrier(0);                                  \
            }                                                                       \
        } while (0)

    #pragma unroll
    for (int tt = 0; tt < 16; tt += 2) {
        STEP(tt,     0, av0, av1);   // load A(tt+2)->av0, stage A(tt+1) from av1
        STEP(tt + 1, 1, av1, av0);   // load A(tt+3)->av1, stage A(tt+2) from av0
    }

    #undef STEP
    #undef STAGE_B
    #undef LOAD_A_TO
    #undef STAGE_A_FROM

    // ---- img row norms (each row fully covered: 2 p x 16 c x 16 steps = 512 c)
    if (act) nrm_parts[p][hwl] = nrm;
    __syncthreads();
    if (tid < 208) {
        float v = 0.f;
        if (tid < 196)
            v = 1.0f / fmaxf(sqrtf(nrm_parts[0][tid] + nrm_parts[1][tid]), 1e-12f);
        rnorm_s[tid] = v;
    }
    __syncthreads();

    // ---- fused epilogue
    float mx[4], sw[4], swa[4];
    #pragma unroll
    for (int mt = 0; mt < 4; mt++) { mx[mt] = -1e30f; sw[mt] = 0.f; swa[mt] = 0.f; }
    float s1n = 0.f, s1d = 0.f, s2n = 0.f, s2d = 0.f;
    const int dmt = (n >> 4) & 3, dq = n >> 6, dl = n & 15;
    const bool isdiag = (q == dq) && (lm == dl);

    #pragma unroll
    for (int ht = 0; ht < 7; ht++) {
        if (ht < HT) {
            int rowb = hh * 112 + ht * 16 + (kk << 2);
            #pragma unroll
            for (int r = 0; r < 4; r++) {
                int hw = rowb + r;
                float rn = rnorm_s[hw];
                bool valid = hw < 196;
                #pragma unroll
                for (int mt = 0; mt < 4; mt++) {
                    float a0 = acc[ht][mt][r] * rn;
                    if (valid) {
                        float wg = 1.0f / (1.0f + __expf((0.65f - a0) * (1.0f / 0.03f)));
                        mx[mt]  = fmaxf(mx[mt], a0);
                        sw[mt] += wg;
                        swa[mt] += wg * a0;
                        if (isdiag && mt == dmt) {
                            out[n * 196 + hw] = a0;                 // A
                            out[116224 + n * 196 + hw] = wg;        // Pos
                            float p2 = 1.0f / (1.0f + __expf((0.40f - a0) * (1.0f / 0.03f)));
                            float ng = 1.0f - p2;
                            out[166400 + n * 196 + hw] = ng;        // Neg
                            s1n += wg * a0; s1d += wg;
                            s2n += ng * a0; s2d += ng;
                        }
                    }
                }
            }
        }
    }

    // cross-lane reduce (lane groups 16 apart hold same m, different rows)
    #pragma unroll
    for (int mt = 0; mt < 4; mt++) {
        float m1 = mx[mt], v1 = sw[mt], v2 = swa[mt];
        m1 = fmaxf(m1, __shfl_xor(m1, 16, 64)); v1 += __shfl_xor(v1, 16, 64); v2 += __shfl_xor(v2, 16, 64);
        m1 = fmaxf(m1, __shfl_xor(m1, 32, 64)); v1 += __shfl_xor(v1, 32, 64); v2 += __shfl_xor(v2, 32, 64);
        if (l < 16) {
            int m = q * 64 + mt * 16 + l;
            red_max[hh][m] = m1; red_sw[hh][m] = v1; red_swa[hh][m] = v2;
        }
    }
    if (isdiag) {
        diag_parts[hh][kk][0] = s1n;
        diag_parts[hh][kk][1] = s1d;
        diag_parts[hh][kk][2] = s2n;
        diag_parts[hh][kk][3] = s2d;
    }
    __syncthreads();

    if (tid < 256) {
        int m = tid;
        float mxv = fmaxf(red_max[0][m], red_max[1][m]);
        float num = red_swa[0][m] + red_swa[1][m];
        float den = red_sw[0][m] + red_sw[1][m];
        float sim = num / den;
        if (m == n) sim *= -99.0f;
        out[50176 + n * 258 + 1 + m] = sim * RLT;
        out[216576 + n * 256 + m] = mxv;
        if (m == n) {
            float t1n = 0.f, t1d = 0.f, t2n = 0.f, t2d = 0.f;
            #pragma unroll
            for (int h2 = 0; h2 < 2; h2++)
                #pragma unroll
                for (int g2 = 0; g2 < 4; g2++) {
                    t1n += diag_parts[h2][g2][0]; t1d += diag_parts[h2][g2][1];
                    t2n += diag_parts[h2][g2][2]; t2d += diag_parts[h2][g2][3];
                }
            out[50176 + n * 258]       = (t1n / t1d) * RLT;
            out[50176 + n * 258 + 257] = (t2n / t2d) * RLT;
        }
    }
}

extern "C" void kernel_launch(void* const* d_in, const int* in_sizes, int n_in,
                              void* d_out, int out_size, void* d_ws, size_t ws_size,
                              hipStream_t stream) {
    const float* img = (const float*)d_in[0];
    const float* aud = (const float*)d_in[1];
    float* out = (float*)d_out;
    _Float16* aud_pk = (_Float16*)d_ws;   // 512*256 fp16 = 256 KB

    prep_aud_pk<<<256, 256, 0, stream>>>(aud, aud_pk);
    av_one<<<256, 512, 0, stream>>>(img, aud_pk, out);
}